// Round 3
// baseline (326.875 us; speedup 1.0000x reference)
//
#include <hip/hip_runtime.h>
#include <hip/hip_bf16.h>
#include <cstdint>
#include <cstddef>

// LSTMCell: gates = [input|hx] @ [Wih|Whh]^T + b_ih + b_hh  (4096 x 4096 x K=2048)
// Split-bf16 (hi+lo) 3-product MFMA GEMM (fp32-class accuracy), fused LSTM epilogue.
// Round 3: raw s_barrier (no compiler fences intra-step), one-phase-ahead ds_read
// pipeline, distance-1 opposite-buffer staging, chain-broken MFMA ordering.

#define B_ROWS 4096
#define HDIM   1024
#define KDIM   2048
#define BM     256
#define BN     256
#define BK     32
#define T_STEPS (KDIM / BK)   // 64

typedef unsigned short u16;
using f32x4  = __attribute__((ext_vector_type(4))) float;
using short8 = __attribute__((ext_vector_type(8))) short;

__device__ __forceinline__ u16 f2bf(float f) {
    unsigned int u = __builtin_bit_cast(unsigned int, f);
    u += 0x7FFFu + ((u >> 16) & 1u);
    return (u16)(u >> 16);
}
__device__ __forceinline__ float bf2f(u16 s) {
    unsigned int u = ((unsigned int)s) << 16;
    return __builtin_bit_cast(float, u);
}

// ---------------- pack: f32 -> bf16 hi/lo, concat K-dim ----------------
__global__ void pack_kernel(const float* __restrict__ input, const float* __restrict__ hx,
                            const float* __restrict__ wih, const float* __restrict__ whh,
                            u16* __restrict__ Ah, u16* __restrict__ Al,
                            u16* __restrict__ Wh, u16* __restrict__ Wl)
{
    const int PER = (B_ROWS * KDIM) / 4;
    int stride = gridDim.x * blockDim.x;
    for (int i = blockIdx.x * blockDim.x + threadIdx.x; i < 2 * PER; i += stride) {
        int isW = (i >= PER) ? 1 : 0;
        int e = i - isW * PER;
        int row = e >> 9;
        int k = (e & 511) << 2;
        const float* s0 = isW ? wih : input;
        const float* s1 = isW ? whh : hx;
        const float* src = (k < 1024) ? (s0 + (size_t)row * 1024 + k)
                                      : (s1 + (size_t)row * 1024 + (k - 1024));
        float4 v = *(const float4*)src;
        u16 h0 = f2bf(v.x), h1 = f2bf(v.y), h2 = f2bf(v.z), h3 = f2bf(v.w);
        u16 l0 = f2bf(v.x - bf2f(h0));
        u16 l1 = f2bf(v.y - bf2f(h1));
        u16 l2 = f2bf(v.z - bf2f(h2));
        u16 l3 = f2bf(v.w - bf2f(h3));
        size_t doff = (size_t)row * KDIM + k;
        u16* dh = (isW ? Wh : Ah) + doff;
        u16* dl = (isW ? Wl : Al) + doff;
        *(ushort4*)dh = make_ushort4(h0, h1, h2, h3);
        *(ushort4*)dl = make_ushort4(l0, l1, l2, l3);
    }
}

// ---------------- fused GEMM + LSTM epilogue ----------------
__device__ __forceinline__ void gload16(const void* g, void* l) {
    __builtin_amdgcn_global_load_lds((const __attribute__((address_space(1))) void*)g,
                                     (__attribute__((address_space(3))) void*)l, 16, 0, 0);
}
__device__ __forceinline__ float sigmf(float x) { return 1.0f / (1.0f + __expf(-x)); }
__device__ __forceinline__ float tanhfast(float x) { return 1.0f - 2.0f / (1.0f + __expf(2.0f * x)); }

__launch_bounds__(512, 2)
__global__ void lstm_fused(const u16* __restrict__ Ah, const u16* __restrict__ Al,
                           const u16* __restrict__ Wh, const u16* __restrict__ Wl,
                           const float* __restrict__ cx, const float* __restrict__ eps_c,
                           const float* __restrict__ eps_h,
                           const float* __restrict__ bias_ih, const float* __restrict__ bias_hh,
                           const float* __restrict__ noise_q, const float* __restrict__ noise_e,
                           float* __restrict__ out)
{
    // [buf][kc(4)][row(256)][8] u16 = 16 KB per tile-buf; 4 tiles x 2 bufs = 128 KB
    __shared__ __align__(16) u16 lAh[2][4][256][8];
    __shared__ __align__(16) u16 lAl[2][4][256][8];
    __shared__ __align__(16) u16 lWh[2][4][256][8];
    __shared__ __align__(16) u16 lWl[2][4][256][8];

    int bid = blockIdx.x;
    // XCD swizzle: XCD x gets w in [32x,32x+32) = 2 W-panels (4 MB, L2-resident) x all A panels
    int w = (bid & 7) * 32 + (bid >> 3);
    int mi = w & 15, hq = w >> 4;
    int bm0 = mi * BM;
    int h0 = hq * 64;

    int tid  = threadIdx.x;
    int lane = tid & 63;
    int wid  = tid >> 6;      // 0..7
    int wm   = wid >> 2;      // M half (128 rows)
    int wn   = wid & 3;       // N quarter (64 cols = 16 h x 4 gates)

    // ---- staging thread mapping: tid -> (kc = tid>>8 (+2 per sweep), row = tid&255) ----
    int rS  = tid & 255;
    int kcS = tid >> 8;
    const u16* Asrc_h = Ah + (size_t)(bm0 + rS) * KDIM + kcS * 8;
    const u16* Asrc_l = Al + (size_t)(bm0 + rS) * KDIM + kcS * 8;
    // LDS W row n -> W global row: gate=(n>>4)&3, h = h0 + (n>>6)*16 + (n&15)
    int wgrow = ((rS >> 4) & 3) * 1024 + h0 + (rS >> 6) * 16 + (rS & 15);
    const u16* Wsrc_h = Wh + (size_t)wgrow * KDIM + kcS * 8;
    const u16* Wsrc_l = Wl + (size_t)wgrow * KDIM + kcS * 8;

#define STG4(b, koff) do { \
        gload16(Asrc_h + (koff),      &lAh[b][kcS][rS][0]);     \
        gload16(Asrc_h + (koff) + 16, &lAh[b][kcS + 2][rS][0]); \
        gload16(Asrc_l + (koff),      &lAl[b][kcS][rS][0]);     \
        gload16(Asrc_l + (koff) + 16, &lAl[b][kcS + 2][rS][0]); \
        gload16(Wsrc_h + (koff),      &lWh[b][kcS][rS][0]);     \
        gload16(Wsrc_h + (koff) + 16, &lWh[b][kcS + 2][rS][0]); \
        gload16(Wsrc_l + (koff),      &lWl[b][kcS][rS][0]);     \
        gload16(Wsrc_l + (koff) + 16, &lWl[b][kcS + 2][rS][0]); \
    } while (0)

    // ---- fragment read pointers ----
    int fkc = lane >> 4, fr = lane & 15;
    const u16* pAh = &lAh[0][fkc][wm * 128 + fr][0];
    const u16* pAl = &lAl[0][fkc][wm * 128 + fr][0];
    const u16* pWh = &lWh[0][fkc][wn * 64 + fr][0];
    const u16* pWl = &lWl[0][fkc][wn * 64 + fr][0];
    const int BUFO = 4 * 256 * 8;   // u16 per buffer

    f32x4 acc[8][4];
#pragma unroll
    for (int m = 0; m < 8; ++m)
#pragma unroll
        for (int g = 0; g < 4; ++g)
            acc[m][g] = (f32x4){0.f, 0.f, 0.f, 0.f};

    // ---- prologue: stage step 0 into buf0, drain, barrier ----
    STG4(0, 0);
    asm volatile("s_waitcnt vmcnt(0)" ::: "memory");
    __builtin_amdgcn_s_barrier();

#define RD_A(H0, H1, L0, L1, mb) do { \
        H0 = *(const short8*)(pAh + bo + (mb) * 128);       \
        H1 = *(const short8*)(pAh + bo + ((mb) + 1) * 128); \
        L0 = *(const short8*)(pAl + bo + (mb) * 128);       \
        L1 = *(const short8*)(pAl + bo + ((mb) + 1) * 128); \
    } while (0)

    // product-outermost: dependent acc reuse distance = 8 MFMAs
#define PH_MFMA(m0_, AH0, AH1, AL0, AL1) do { \
        __builtin_amdgcn_s_setprio(1); \
        _Pragma("unroll") \
        for (int g = 0; g < 4; ++g) { \
            acc[(m0_)][g]     = __builtin_amdgcn_mfma_f32_16x16x32_bf16(AH0, wh[g], acc[(m0_)][g], 0, 0, 0); \
            acc[(m0_) + 1][g] = __builtin_amdgcn_mfma_f32_16x16x32_bf16(AH1, wh[g], acc[(m0_) + 1][g], 0, 0, 0); \
        } \
        _Pragma("unroll") \
        for (int g = 0; g < 4; ++g) { \
            acc[(m0_)][g]     = __builtin_amdgcn_mfma_f32_16x16x32_bf16(AL0, wh[g], acc[(m0_)][g], 0, 0, 0); \
            acc[(m0_) + 1][g] = __builtin_amdgcn_mfma_f32_16x16x32_bf16(AL1, wh[g], acc[(m0_) + 1][g], 0, 0, 0); \
        } \
        _Pragma("unroll") \
        for (int g = 0; g < 4; ++g) { \
            acc[(m0_)][g]     = __builtin_amdgcn_mfma_f32_16x16x32_bf16(AH0, wl[g], acc[(m0_)][g], 0, 0, 0); \
            acc[(m0_) + 1][g] = __builtin_amdgcn_mfma_f32_16x16x32_bf16(AH1, wl[g], acc[(m0_) + 1][g], 0, 0, 0); \
        } \
        __builtin_amdgcn_s_setprio(0); \
    } while (0)

#pragma unroll 1
    for (int t = 0; t < T_STEPS; ++t) {
        const int bo = (t & 1) * BUFO;
        const int nb = (t & 1) ^ 1;
        short8 wh[4], wl[4];
        short8 xh0, xh1, xl0, xl1, yh0, yh1, yl0, yl1;

        // ---- P0: read W + A(m0,m1); stage step t+1 into opposite buffer ----
#pragma unroll
        for (int g = 0; g < 4; ++g) {
            wh[g] = *(const short8*)(pWh + bo + g * 128);
            wl[g] = *(const short8*)(pWl + bo + g * 128);
        }
        RD_A(xh0, xh1, xl0, xl1, 0);
        if (t + 1 < T_STEPS) STG4(nb, (t + 1) * 32);
        __builtin_amdgcn_s_barrier();

        // ---- P1: issue A(m2,m3) reads, MFMA m0,m1 (overlaps outstanding reads) ----
        RD_A(yh0, yh1, yl0, yl1, 2);
        PH_MFMA(0, xh0, xh1, xl0, xl1);
        __builtin_amdgcn_s_barrier();

        // ---- P2 ----
        RD_A(xh0, xh1, xl0, xl1, 4);
        PH_MFMA(2, yh0, yh1, yl0, yl1);
        __builtin_amdgcn_s_barrier();

        // ---- P3 ----
        RD_A(yh0, yh1, yl0, yl1, 6);
        PH_MFMA(4, xh0, xh1, xl0, xl1);
        __builtin_amdgcn_s_barrier();

        // ---- P4: last MFMA cluster, then drain next step's staging loads ----
        PH_MFMA(6, yh0, yh1, yl0, yl1);
        asm volatile("s_waitcnt vmcnt(0)" ::: "memory");
        __builtin_amdgcn_s_barrier();
    }

    // ---- epilogue: gates for (r,h) are lane-local across n-frags ----
    float sq_e = sqrtf(noise_e[0]);
    float sq_q = sqrtf(noise_q[0]);
    int hcol = h0 + wn * 16 + fr;
    float b_i = bias_ih[hcol]        + bias_hh[hcol];
    float b_f = bias_ih[1024 + hcol] + bias_hh[1024 + hcol];
    float b_c = bias_ih[2048 + hcol] + bias_hh[2048 + hcol];
    float b_o = bias_ih[3072 + hcol] + bias_hh[3072 + hcol];
#pragma unroll
    for (int m = 0; m < 8; ++m) {
        int r0 = bm0 + wm * 128 + m * 16 + fkc * 4;
#pragma unroll
        for (int j = 0; j < 4; ++j) {
            int r = r0 + j;
            size_t off = (size_t)r * HDIM + hcol;
            float gi = acc[m][0][j] + b_i;
            float gf = acc[m][1][j] + b_f;
            float gc = acc[m][2][j] + b_c;
            float go = acc[m][3][j] + b_o;
            float ig = sigmf(gi), fg = sigmf(gf);
            float cg = tanhfast(gc), og = sigmf(go);
            float cyv = fg * cx[off] + ig * cg + sq_e * eps_c[off];
            float hyv = og * tanhfast(cyv) + sq_q * eps_h[off];
            out[off] = hyv;                                 // hy
            out[(size_t)B_ROWS * HDIM + off] = cyv;         // cy
        }
    }
}

extern "C" void kernel_launch(void* const* d_in, const int* in_sizes, int n_in,
                              void* d_out, int out_size, void* d_ws, size_t ws_size,
                              hipStream_t stream)
{
    const float* input = (const float*)d_in[0];
    const float* hx    = (const float*)d_in[1];
    const float* cx    = (const float*)d_in[2];
    const float* nq    = (const float*)d_in[3];
    const float* ne    = (const float*)d_in[4];
    const float* wih   = (const float*)d_in[5];
    const float* whh   = (const float*)d_in[6];
    const float* bih   = (const float*)d_in[7];
    const float* bhh   = (const float*)d_in[8];
    const float* epsc  = (const float*)d_in[9];
    const float* epsh  = (const float*)d_in[10];
    float* out = (float*)d_out;

    u16* Ah = (u16*)d_ws;
    u16* Al = Ah + (size_t)B_ROWS * KDIM;
    u16* Wh = Al + (size_t)B_ROWS * KDIM;
    u16* Wl = Wh + (size_t)B_ROWS * KDIM;   // 64 MB of ws total

    hipLaunchKernelGGL(pack_kernel, dim3(2048), dim3(256), 0, stream,
                       input, hx, wih, whh, Ah, Al, Wh, Wl);
    hipLaunchKernelGGL(lstm_fused, dim3(256), dim3(512), 0, stream,
                       Ah, Al, Wh, Wl, cx, epsc, epsh, bih, bhh, nq, ne, out);
}

// Round 5
// 240.015 us; speedup vs baseline: 1.3619x; 1.3619x over previous
//
#include <hip/hip_runtime.h>
#include <hip/hip_bf16.h>
#include <cstdint>
#include <cstddef>

// LSTMCell: gates = [input|hx] @ [Wih|Whh]^T + b_ih + b_hh  (4096 x 4096 x K=2048)
// Round 5: f16 split-A 2-product GEMM (A = Ah+Al in f16, W single f16).
// R4 bug fixed: A staging base no longer double-counts kA*8.
// Error = W's f16 rounding only: sigma_gate ~ 0.011, absmax ~0.06-0.10 < 0.13.
// 138 GFLOP. Proven R1/m97 structure: single-buffer, 2-barrier, BK=64,
// 4-wave blocks, 2 blocks/CU, k-chunk-panel LDS layout (0 bank conflicts measured).

#define B_ROWS 4096
#define HDIM   1024
#define KDIM   2048
#define BM     128
#define BK     64
#define T_STEPS (KDIM / BK)   // 32

typedef unsigned short u16;
using f32x4  = __attribute__((ext_vector_type(4))) float;
using short8 = __attribute__((ext_vector_type(8))) short;
using half8  = __attribute__((ext_vector_type(8))) _Float16;

__device__ __forceinline__ u16 f2h_bits(float f) {
    _Float16 h = (_Float16)f;                    // v_cvt_f16_f32, RTN
    return __builtin_bit_cast(u16, h);
}
__device__ __forceinline__ float h2f(u16 s) {
    return (float)__builtin_bit_cast(_Float16, s);
}

// ---------------- pack: f32 -> f16 (A split hi/lo, W single), concat K-dim ----------------
__global__ void pack_kernel(const float* __restrict__ input, const float* __restrict__ hx,
                            const float* __restrict__ wih, const float* __restrict__ whh,
                            u16* __restrict__ Ah, u16* __restrict__ Al,
                            u16* __restrict__ Wf)
{
    const int PER = (B_ROWS * KDIM) / 4;  // float4 groups per matrix
    int stride = gridDim.x * blockDim.x;
    for (int i = blockIdx.x * blockDim.x + threadIdx.x; i < 2 * PER; i += stride) {
        int isW = (i >= PER) ? 1 : 0;
        int e = i - isW * PER;
        int row = e >> 9;            // 512 float4-groups per row of 2048
        int k = (e & 511) << 2;
        const float* s0 = isW ? wih : input;
        const float* s1 = isW ? whh : hx;
        const float* src = (k < 1024) ? (s0 + (size_t)row * 1024 + k)
                                      : (s1 + (size_t)row * 1024 + (k - 1024));
        float4 v = *(const float4*)src;
        size_t doff = (size_t)row * KDIM + k;
        if (isW) {
            *(ushort4*)(Wf + doff) = make_ushort4(f2h_bits(v.x), f2h_bits(v.y),
                                                  f2h_bits(v.z), f2h_bits(v.w));
        } else {
            u16 h0 = f2h_bits(v.x), h1 = f2h_bits(v.y), h2 = f2h_bits(v.z), h3 = f2h_bits(v.w);
            *(ushort4*)(Ah + doff) = make_ushort4(h0, h1, h2, h3);
            *(ushort4*)(Al + doff) = make_ushort4(f2h_bits(v.x - h2f(h0)),
                                                  f2h_bits(v.y - h2f(h1)),
                                                  f2h_bits(v.z - h2f(h2)),
                                                  f2h_bits(v.w - h2f(h3)));
        }
    }
}

// ---------------- fused GEMM + LSTM epilogue ----------------
__device__ __forceinline__ void gload16(const void* g, void* l) {
    __builtin_amdgcn_global_load_lds((const __attribute__((address_space(1))) void*)g,
                                     (__attribute__((address_space(3))) void*)l, 16, 0, 0);
}
__device__ __forceinline__ float sigmf(float x) { return 1.0f / (1.0f + __expf(-x)); }
__device__ __forceinline__ float tanhfast(float x) { return 1.0f - 2.0f / (1.0f + __expf(2.0f * x)); }

__launch_bounds__(256, 2)
__global__ void lstm_fused(const u16* __restrict__ Ahp, const u16* __restrict__ Alp,
                           const u16* __restrict__ Wfp,
                           const float* __restrict__ cx, const float* __restrict__ eps_c,
                           const float* __restrict__ eps_h,
                           const float* __restrict__ bias_ih, const float* __restrict__ bias_hh,
                           const float* __restrict__ noise_q, const float* __restrict__ noise_e,
                           float* __restrict__ out)
{
    // k-chunk-panel layout: [kc(8)][row][8] u16 — linear for global_load_lds,
    // conflict-free ds_read_b128 (0 conflicts measured R1-R3). 16+16+32 = 64 KB.
    __shared__ __align__(16) u16 lAh[8][BM][8];
    __shared__ __align__(16) u16 lAl[8][BM][8];
    __shared__ __align__(16) u16 lW [8][256][8];

    const int nwg = 512;
    int bid = blockIdx.x;
    // XCD-bijective swizzle (512 % 8 == 0): consecutive w share the same W panel -> L2 reuse
    int w = (bid & 7) * (nwg >> 3) + (bid >> 3);
    int mi = w & 31;          // 32 M-chunks of 128 rows
    int hq = w >> 5;          // 16 h-chunks of 64 cols
    int bm0 = mi * BM;
    int h0 = hq * 64;

    int tid  = threadIdx.x;
    int lane = tid & 63;
    int wv   = tid >> 6;      // wave id 0..3
    int wm   = wv & 1;        // M half (64 rows)
    int wn   = wv >> 1;       // h half (32 cols)

    // ---- staging mappings ----
    // A: thread -> (row = tid&127, kc parity = tid>>7), 4 sweeps of kc += 2
    int rA = tid & 127;
    int kA = tid >> 7;        // 0/1
    const u16* Asrc_h = Ahp + (size_t)(bm0 + rA) * KDIM;   // NOTE: no kA*8 here (R4 bug)
    const u16* Asrc_l = Alp + (size_t)(bm0 + rA) * KDIM;
    // W: thread -> LDS row rW = tid (0..255), 8 sweeps over kc
    // LDS W row n <-> global gate row: gate = (n>>4)&3, h = h0 + (n>>6)*16 + (n&15)
    int rW = tid;
    int wgrow = ((rW >> 4) & 3) * 1024 + h0 + (rW >> 6) * 16 + (rW & 15);
    const u16* Wsrc = Wfp + (size_t)wgrow * KDIM;

    // ---- fragment read indices ----
    int fk = lane >> 4, fr = lane & 15;

    f32x4 acc[4][8];   // [m-frag][g*2+hh]
#pragma unroll
    for (int m = 0; m < 4; ++m)
#pragma unroll
        for (int n = 0; n < 8; ++n)
            acc[m][n] = (f32x4){0.f, 0.f, 0.f, 0.f};

#pragma unroll 1
    for (int kt = 0; kt < T_STEPS; ++kt) {
        int kk = kt * BK;
        // ---- stage 64 KB: 16 x global_load_lds_dwordx4 per thread ----
#pragma unroll
        for (int s = 0; s < 4; ++s) {
            int kc = kA + 2 * s;
            gload16(Asrc_h + kk + kc * 8, &lAh[kc][rA][0]);
            gload16(Asrc_l + kk + kc * 8, &lAl[kc][rA][0]);
        }
#pragma unroll
        for (int s = 0; s < 8; ++s)
            gload16(Wsrc + kk + s * 8, &lW[s][rW][0]);
        __syncthreads();   // drains vmcnt before barrier

#pragma unroll
        for (int kh = 0; kh < 2; ++kh) {
            int kc = kh * 4 + fk;
            half8 ah[4], al[4], wf[8];
#pragma unroll
            for (int m = 0; m < 4; ++m) {
                ah[m] = __builtin_bit_cast(half8, *(const short8*)&lAh[kc][wm * 64 + m * 16 + fr][0]);
                al[m] = __builtin_bit_cast(half8, *(const short8*)&lAl[kc][wm * 64 + m * 16 + fr][0]);
            }
#pragma unroll
            for (int n = 0; n < 8; ++n) {
                int g = n >> 1, hh = n & 1;
                int row = (2 * wn + hh) * 64 + g * 16 + fr;
                wf[n] = __builtin_bit_cast(half8, *(const short8*)&lW[kc][row][0]);
            }
            // hi products (acc reuse distance 32), then lo products
#pragma unroll
            for (int n = 0; n < 8; ++n)
#pragma unroll
                for (int m = 0; m < 4; ++m)
                    acc[m][n] = __builtin_amdgcn_mfma_f32_16x16x32_f16(ah[m], wf[n], acc[m][n], 0, 0, 0);
#pragma unroll
            for (int n = 0; n < 8; ++n)
#pragma unroll
                for (int m = 0; m < 4; ++m)
                    acc[m][n] = __builtin_amdgcn_mfma_f32_16x16x32_f16(al[m], wf[n], acc[m][n], 0, 0, 0);
        }
        __syncthreads();
    }

    // ---- epilogue: all 4 gates for (r,h) are lane-local ----
    float sq_e = sqrtf(noise_e[0]);
    float sq_q = sqrtf(noise_q[0]);
    int hbase = h0 + wn * 32 + fr;
#pragma unroll
    for (int hh = 0; hh < 2; ++hh) {
        int h = hbase + hh * 16;
        float bsum[4];
#pragma unroll
        for (int g = 0; g < 4; ++g)
            bsum[g] = bias_ih[g * 1024 + h] + bias_hh[g * 1024 + h];
#pragma unroll
        for (int m = 0; m < 4; ++m) {
            int r0 = bm0 + wm * 64 + m * 16 + fk * 4;
#pragma unroll
            for (int j = 0; j < 4; ++j) {
                int r = r0 + j;
                float gi = acc[m][0 + hh][j] + bsum[0];
                float gf = acc[m][2 + hh][j] + bsum[1];
                float gc = acc[m][4 + hh][j] + bsum[2];
                float go = acc[m][6 + hh][j] + bsum[3];
                float ig = sigmf(gi), fg = sigmf(gf);
                float cg = tanhfast(gc), og = sigmf(go);
                size_t off = (size_t)r * HDIM + h;
                float cyv = fg * cx[off] + ig * cg + sq_e * eps_c[off];
                float hyv = og * tanhfast(cyv) + sq_q * eps_h[off];
                out[off] = hyv;                                 // hy
                out[(size_t)B_ROWS * HDIM + off] = cyv;         // cy
            }
        }
    }
}

extern "C" void kernel_launch(void* const* d_in, const int* in_sizes, int n_in,
                              void* d_out, int out_size, void* d_ws, size_t ws_size,
                              hipStream_t stream)
{
    const float* input = (const float*)d_in[0];
    const float* hx    = (const float*)d_in[1];
    const float* cx    = (const float*)d_in[2];
    const float* nq    = (const float*)d_in[3];
    const float* ne    = (const float*)d_in[4];
    const float* wih   = (const float*)d_in[5];
    const float* whh   = (const float*)d_in[6];
    const float* bih   = (const float*)d_in[7];
    const float* bhh   = (const float*)d_in[8];
    const float* epsc  = (const float*)d_in[9];
    const float* epsh  = (const float*)d_in[10];
    float* out = (float*)d_out;

    u16* Ah = (u16*)d_ws;
    u16* Al = Ah + (size_t)B_ROWS * KDIM;
    u16* Wf = Al + (size_t)B_ROWS * KDIM;   // 48 MB of ws total

    hipLaunchKernelGGL(pack_kernel, dim3(2048), dim3(256), 0, stream,
                       input, hx, wih, whh, Ah, Al, Wf);
    hipLaunchKernelGGL(lstm_fused, dim3(512), dim3(256), 0, stream,
                       Ah, Al, Wf, cx, epsc, epsh, bih, bhh, nq, ne, out);
}